// Round 14
// baseline (60.789 us; speedup 1.0000x reference)
//
#include <hip/hip_runtime.h>
#include <math.h>

// MovingZScoreNorm: x[32,8192,128] f32, W=24.
// R14: dwordx4 row-pair restructure. Lane l: half h=l>>5, m=l&31 owns
// channels 4m..4m+3; half 0 processes even rows, half 1 odd rows. One
// dwordx4 load/store instruction covers TWO rows (1024B/wave). Per-parity
// register pipelines; cross-parity window halves combined via
// permlane32_swap each step (h=0 uses partner's PREVIOUS step value,
// h=1 the current -- window [q-11,q+12] parity split is asymmetric).
// sq_tot: 32-lane half-reduce (permlane16_swap + DPP ror 8/4/2/1) serves
// both rows of the pair at once. Steps/tile 84 vs 156; ~same bytes.
//
// Rings (all static indices): x = 2 banks x 12 f4 (24 row-pairs, swap
// banks per chunk); st ring 12 (read-then-write same slot); winD ring 6.
// partner = (swap.x + swap.y) - own  (R11-proven semantics, placement-free).

constexpr int Sdim = 8192;
constexpr int Cdim = 128;
constexpr int TT   = 128;            // rows per wave-tile
constexpr int NTb  = Sdim / TT;      // 64 tiles per batch
constexpr float EPSv = 1e-7f;

typedef float f4 __attribute__((ext_vector_type(4)));
typedef unsigned int u2 __attribute__((ext_vector_type(2)));

template<int N>
__device__ __forceinline__ float dpp_ror_add(float v) {
    int r = __builtin_amdgcn_update_dpp(0, __float_as_int(v),
                                        0x120 | N, 0xf, 0xf, true);
    return v + __int_as_float(r);
}

// sum over the lane's own 32-lane half (both halves in one inst stream)
__device__ __forceinline__ float half_allsum(float v) {
    unsigned u = __float_as_uint(v);
    u2 r = __builtin_amdgcn_permlane16_swap(u, u, false, false);
    v = __uint_as_float(r.x) + __uint_as_float(r.y);   // + v[l^16]
    v = dpp_ror_add<8>(v);
    v = dpp_ror_add<4>(v);
    v = dpp_ror_add<2>(v);
    v = dpp_ror_add<1>(v);
    return v;
}

// partner lane's (l^32) value: placement-free via sum-minus
__device__ __forceinline__ float partner_swap(float v) {
    unsigned u = __float_as_uint(v);
    u2 r = __builtin_amdgcn_permlane32_swap(u, u, false, false);
    return (__uint_as_float(r.x) + __uint_as_float(r.y)) - v;
}

__device__ __forceinline__ f4 partner_swap4(f4 v) {
    f4 o;
    o.x = partner_swap(v.x);
    o.y = partner_swap(v.y);
    o.z = partner_swap(v.z);
    o.w = partner_swap(v.w);
    return o;
}

template<bool EDGE>
__device__ __forceinline__ f4 ld4(const float* __restrict__ bp, int row) {
    if (EDGE && (unsigned)row >= (unsigned)Sdim) { f4 z = {0.f,0.f,0.f,0.f}; return z; }
    return *reinterpret_cast<const f4*>(bp + (size_t)row * Cdim);
}

__device__ __forceinline__ int cnt_of(int r) {
    return min(r + 12, Sdim - 1) - max(r - 11, 0) + 1;
}

// One chunk of 12 steps, t = cb..cb+11. P,Q are the x banks (swapped per
// chunk parity). Step t: own rows g(k)=2k+h; reads g(t-12)=P[j],
// g(t-6)=j<6?P[j+6]:Q[j-6], g(t)=Q[j]; load writes g(t+11) into
// (j==0?Q[11]:P[j-1]).
template<bool EDGE, bool LOAD>
__device__ __forceinline__ void chunk12(
    const float* __restrict__ xb, float* __restrict__ yb,
    f4 (&P)[12], f4 (&Q)[12], float (&stR)[12], f4 (&winD)[6],
    f4& ownWin, f4& pPrevWin, float& varOwn, float& pPrevVar,
    int cb, int k0, int hi)
{
#pragma unroll
    for (int j = 0; j < 12; ++j) {
        const int t = cb + j;
        const f4 xold = P[j];                       // row g(t-12) = output row
        if (LOAD) {
            const int lr = 2 * (t + 11) + hi;       // row g(t+11)
            const f4 v = ld4<EDGE>(xb, lr);
            if (j == 0) Q[11] = v; else P[j - 1] = v;
        }
        const f4 xmid = (j < 6) ? P[j + 6] : Q[j - 6];   // g(t-6)
        const f4 xcur = Q[j];                            // g(t)
        ownWin += xcur - xold;                      // own-parity win for k=t-6
        const f4 pc = partner_swap4(ownWin);
        const f4 useW = hi ? pc : pPrevWin;         // parity asymmetry
        pPrevWin = pc;
        const f4 winF = ownWin + useW;              // full 24-row window, row s6

        const int s6 = 2 * (t - 6) + hi;
        float ic6;
        if (EDGE) ic6 = __builtin_amdgcn_rcpf((float)cnt_of(s6));
        else      ic6 = 1.f / 24.f;
        const f4 dx = xmid - winF * ic6;
        float p = dx.x * dx.x + dx.y * dx.y + dx.z * dx.z + dx.w * dx.w;
        if (EDGE && (unsigned)s6 >= (unsigned)Sdim) p = 0.f;  // zero-pad sq
        p = half_allsum(p);                         // sq_tot(s6), own half

        varOwn += p - stR[j];                       // own-parity var win, k=t-12
        stR[j] = p;
        const float pv = partner_swap(varOwn);
        const float useV = hi ? pv : pPrevVar;
        pPrevVar = pv;

        const f4 winq = winD[j % 6];                // win(q), q = g(t-12)
        winD[j % 6] = winF;

        const int kq = t - 12;
        if (kq >= k0 && kq < k0 + TT / 2) {
            const int q = 2 * kq + hi;
            float iq;
            if (EDGE) iq = __builtin_amdgcn_rcpf((float)cnt_of(q));
            else      iq = 1.f / 24.f;
            const float istd = __builtin_amdgcn_rcpf(
                __builtin_amdgcn_sqrtf(fmaxf(varOwn + useV, 0.f) * (1.f / 23.f))
                + EPSv);
            const f4 o = (xold - winq * iq) * istd;
            *reinterpret_cast<f4*>(yb + (size_t)q * Cdim) = o;
        }
    }
}

template<bool EDGE>
__device__ __forceinline__ void run_tile(
    const float* __restrict__ xb, float* __restrict__ yb, int t0, int hi)
{
    const int k0 = t0 >> 1;                // own-parity step index of 1st output
    f4 P[12], Q[12], winD[6];
    float stR[12];

    // Preload 23 row-pairs: slot li holds g(k0-20+li) = row t0-40+2*li+hi.
#pragma unroll
    for (int li = 0; li < 12; ++li) P[li] = ld4<EDGE>(xb, t0 - 40 + 2 * li + hi);
#pragma unroll
    for (int li = 12; li < 23; ++li) Q[li - 12] = ld4<EDGE>(xb, t0 - 40 + 2 * li + hi);

    f4 ownWin = P[0];
#pragma unroll
    for (int li = 1; li < 12; ++li) ownWin += P[li];   // g(t_s-12..t_s-1)

    f4 pPrevWin = {0.f, 0.f, 0.f, 0.f};
    float varOwn = 0.f, pPrevVar = 0.f;
#pragma unroll
    for (int i = 0; i < 12; ++i) stR[i] = 0.f;
#pragma unroll
    for (int i = 0; i < 6; ++i) { f4 z = {0.f,0.f,0.f,0.f}; winD[i] = z; }

    // 7 chunks of 12 steps: t = k0-8 .. k0+75 (outputs kq = k0 .. k0+63).
    int cb = k0 - 8;
#pragma unroll 1
    for (int c = 0; c < 3; ++c) {
        chunk12<EDGE, true>(xb, yb, P, Q, stR, winD, ownWin, pPrevWin,
                            varOwn, pPrevVar, cb, k0, hi); cb += 12;
        chunk12<EDGE, true>(xb, yb, Q, P, stR, winD, ownWin, pPrevWin,
                            varOwn, pPrevVar, cb, k0, hi); cb += 12;
    }
    chunk12<EDGE, false>(xb, yb, P, Q, stR, winD, ownWin, pPrevWin,
                         varOwn, pPrevVar, cb, k0, hi);
}

__global__ __launch_bounds__(256, 2)
void mzs_kernel(const float* __restrict__ x, float* __restrict__ y) {
    const int tid  = threadIdx.x;
    const int lane = tid & 63;
    const int hi   = lane >> 5;                     // row parity half
    const int m    = lane & 31;                     // channel group
    const int wid  = blockIdx.x * 4 + (tid >> 6);   // 2048 wave-tiles
    const int b    = wid >> 6;                      // 64 tiles per batch
    const int ti   = wid & 63;
    const int t0   = ti * TT;
    const float* xb = x + (size_t)b * Sdim * Cdim + m * 4;
    float*       yb = y + (size_t)b * Sdim * Cdim + m * 4;
    if (ti == 0 || ti == NTb - 1) run_tile<true >(xb, yb, t0, hi);
    else                          run_tile<false>(xb, yb, t0, hi);
}

extern "C" void kernel_launch(void* const* d_in, const int* in_sizes, int n_in,
                              void* d_out, int out_size, void* d_ws, size_t ws_size,
                              hipStream_t stream) {
    const float* x = (const float*)d_in[0];
    float* y = (float*)d_out;
    // 2048 wave-tiles (32 batches x 64 tiles), 4 waves per 256-thread block
    mzs_kernel<<<dim3(512), dim3(256), 0, stream>>>(x, y);
}

// Round 15
// 53.561 us; speedup vs baseline: 1.1350x; 1.1350x over previous
//
#include <hip/hip_runtime.h>
#include <math.h>

// MovingZScoreNorm: x[32,8192,128] f32, W=24.
// mean: TF SAME avg-pool with valid-count; var: windowed sum of channel-summed
// sq / (W-1); out = (x-mean)/(sqrt(var)+eps).
//
// One wave per (batch, 256-row tile); lane owns 2 channels (float2).
// Single global load per iteration: x(s+24); 36-row register delay line
// (3 rotating banks x 12). Output mean = lead window-sum delayed 12 iters.
// Per-lane variance running-sum; batched all-VALU 64-lane allreduce
// (permlane32/16 swap builtins + DPP row_ror tree) per 4 output rows.
//
// R15: TT=256 (halo amortization). vmem traffic model: R11 = 323 MB @
// 55.7us = 5.9 TB/s ~ 94% of m13 copy ceiling; TT=256 cuts traffic to
// 298 MB (-7.8%). Grid: 1024 waves = 256 blocks = 1 block/CU (1 wave/SIMD
// -- R4/R12 showed wave-count insensitivity).

constexpr int Sdim = 8192;
constexpr int Cdim = 128;
constexpr int TT   = 256;            // output rows per wave
constexpr int NTb  = Sdim / TT;      // 32 tiles per batch
constexpr float EPSv = 1e-7f;

typedef unsigned int uintx2 __attribute__((ext_vector_type(2)));

template<bool EDGE>
__device__ __forceinline__ float2 ldg(const float* __restrict__ base, int r) {
    if (EDGE && (unsigned)r >= (unsigned)Sdim) return make_float2(0.f, 0.f);
    return *reinterpret_cast<const float2*>(base + (size_t)r * Cdim);
}

__device__ __forceinline__ void st2(float* p, float a, float b) {
    *reinterpret_cast<float2*>(p) = make_float2(a, b);
}

template<int N>
__device__ __forceinline__ float dpp_ror_add(float v) {
    // v + row_ror:N(v)   (rotation within each 16-lane row; VALU pipe)
    int r = __builtin_amdgcn_update_dpp(0, __float_as_int(v),
                                        0x120 | N, 0xf, 0xf, true);
    return v + __int_as_float(r);
}

__device__ __forceinline__ float swap32_add(float v) {
    const unsigned u = __float_as_uint(v);
    uintx2 r = __builtin_amdgcn_permlane32_swap(u, u, false, false);
    return __uint_as_float(r.x) + __uint_as_float(r.y);  // v[l]+v[l^32]
}

__device__ __forceinline__ float swap16_add(float v) {
    const unsigned u = __float_as_uint(v);
    uintx2 r = __builtin_amdgcn_permlane16_swap(u, u, false, false);
    return __uint_as_float(r.x) + __uint_as_float(r.y);  // v[l]+v[l^16]
}

__device__ __forceinline__ float wave_allsum(float v) {
    v = swap32_add(v);
    v = swap16_add(v);
    v = dpp_ror_add<8>(v);
    v = dpp_ror_add<4>(v);
    v = dpp_ror_add<2>(v);
    v = dpp_ror_add<1>(v);
    return v;                // total of 64 lanes, in every lane
}

// One chunk of NJ iterations s = cb..cb+NJ-1 (NJ % 4 == 0).
template<bool EDGE, bool LOAD, int NJ>
__device__ __forceinline__ void chunkN(
    const float* __restrict__ base, float* __restrict__ obase,
    float2 (&Xw)[12], float2 (&Xm)[12], float2 (&Xn)[12],
    float (&Tw)[12], float (&Tr)[12], float2 (&Lb)[12],
    float2& lead, float& varsum, int cb, int t0)
{
    float2 onum[4];                  // per-row output numerators (batch of 4)
    float  vs4[4];                   // per-lane varsum snapshots
#pragma unroll
    for (int j = 0; j < NJ; ++j) {
        const int s = cb + j;
        const float2 xold = Xw[j];                 // x(s-12)
        if (LOAD) Xw[j] = ldg<EDGE>(base, s + 24); // consumed 12 iters later
        const float2 xmid = Xn[j];                 // x(s+12)
        lead.x += xmid.x - xold.x;                 // lead -> winsum(s)
        lead.y += xmid.y - xold.y;
        const float2 xcur = Xm[j];                 // x(s)
        float invc;
        if (EDGE) {
            const int cnt = min(s + 12, Sdim - 1) - max(s - 11, 0) + 1;
            invc = __builtin_amdgcn_rcpf((float)cnt);
        } else {
            invc = 1.f / 24.f;
        }
        const float dx = xcur.x - lead.x * invc;
        const float dy = xcur.y - lead.y * invc;
        float st = dx * dx + dy * dy;              // PER-LANE (2 channels)
        if (EDGE && (unsigned)s >= (unsigned)Sdim) st = 0.f;  // zero-pad sq
        varsum += st - Tr[j];                      // per-lane window sum
        Tw[j] = st;
        const float2 wq = Lb[j];                   // winsum(q), q = s-12
        Lb[j] = lead;
        float invq;
        if (EDGE) {
            const int q = s - 12;
            const int cq = min(q + 12, Sdim - 1) - max(q - 11, 0) + 1;
            invq = __builtin_amdgcn_rcpf((float)cq);
        } else {
            invq = 1.f / 24.f;
        }
        onum[j & 3].x = xold.x - wq.x * invq;      // (x(q) - mean(q))
        onum[j & 3].y = xold.y - wq.y * invq;
        vs4[j & 3] = varsum;

        if ((j & 3) == 3) {                        // batch of 4 output rows
            const int q0 = s - 15;                 // q0..q0+3 (4-aligned vs t0)
            if (q0 >= t0 && q0 < t0 + TT) {
                const float r0 = wave_allsum(vs4[0]);
                const float r1 = wave_allsum(vs4[1]);
                const float r2 = wave_allsum(vs4[2]);
                const float r3 = wave_allsum(vs4[3]);
                const float i0 = __builtin_amdgcn_rcpf(
                    __builtin_amdgcn_sqrtf(fmaxf(r0, 0.f) * (1.f / 23.f)) + EPSv);
                const float i1 = __builtin_amdgcn_rcpf(
                    __builtin_amdgcn_sqrtf(fmaxf(r1, 0.f) * (1.f / 23.f)) + EPSv);
                const float i2 = __builtin_amdgcn_rcpf(
                    __builtin_amdgcn_sqrtf(fmaxf(r2, 0.f) * (1.f / 23.f)) + EPSv);
                const float i3 = __builtin_amdgcn_rcpf(
                    __builtin_amdgcn_sqrtf(fmaxf(r3, 0.f) * (1.f / 23.f)) + EPSv);
                st2(obase + (size_t)(q0    ) * Cdim, onum[0].x * i0, onum[0].y * i0);
                st2(obase + (size_t)(q0 + 1) * Cdim, onum[1].x * i1, onum[1].y * i1);
                st2(obase + (size_t)(q0 + 2) * Cdim, onum[2].x * i2, onum[2].y * i2);
                st2(obase + (size_t)(q0 + 3) * Cdim, onum[3].x * i3, onum[3].y * i3);
            }
        }
    }
}

template<bool EDGE>
__device__ __forceinline__ void run_tile(
    const float* __restrict__ base, float* __restrict__ obase, int t0)
{
    float2 X0[12], X1[12], X2[12], Lb[12];
    float  T0[12], T1[12], T2[12];
    float2 lead = make_float2(0.f, 0.f);
    float  varsum = 0.f;

    // Preload: X0 = x(t0-24+j), X1 = x(t0-12+j), X2 = x(t0+j);
    // lead = winsum(t0-13) = sum x[t0-24 .. t0-1] = sum(X0+X1).
#pragma unroll
    for (int j = 0; j < 12; ++j) {
        X0[j] = ldg<EDGE>(base, t0 - 24 + j);
        X1[j] = ldg<EDGE>(base, t0 - 12 + j);
        X2[j] = ldg<EDGE>(base, t0 + j);
        T0[j] = 0.f; T1[j] = 0.f; T2[j] = 0.f;
        Lb[j] = make_float2(0.f, 0.f);
        lead.x += X0[j].x + X1[j].x;
        lead.y += X0[j].y + X1[j].y;
    }

    // 23 LOAD chunks of 12 + final 4-iter no-LOAD chunk:
    // s = t0-12 .. t0+267 (outputs q = t0 .. t0+255).
    int cb = t0 - 12;
#pragma unroll 1
    for (int k = 0; k < 7; ++k) {   // 3-chunk rotation, statically indexed
        chunkN<EDGE, true, 12>(base, obase, X0, X1, X2, T0, T1, Lb, lead, varsum, cb, t0); cb += 12;
        chunkN<EDGE, true, 12>(base, obase, X1, X2, X0, T1, T2, Lb, lead, varsum, cb, t0); cb += 12;
        chunkN<EDGE, true, 12>(base, obase, X2, X0, X1, T2, T0, Lb, lead, varsum, cb, t0); cb += 12;
    }
    chunkN<EDGE, true , 12>(base, obase, X0, X1, X2, T0, T1, Lb, lead, varsum, cb, t0); cb += 12;  // 22
    chunkN<EDGE, true , 12>(base, obase, X1, X2, X0, T1, T2, Lb, lead, varsum, cb, t0); cb += 12;  // 23
    chunkN<EDGE, false,  4>(base, obase, X2, X0, X1, T2, T0, Lb, lead, varsum, cb, t0);            // 24th
}

__global__ __launch_bounds__(256, 2)
void mzs_kernel(const float* __restrict__ x, float* __restrict__ y) {
    const int tid  = threadIdx.x;
    const int lane = tid & 63;
    const int wid  = blockIdx.x * 4 + (tid >> 6);   // 1024 waves
    const int b    = wid >> 5;                      // 32 tiles per batch
    const int ti   = wid & 31;
    const int t0   = ti * TT;
    const float* base  = x + (size_t)b * Sdim * Cdim + lane * 2;
    float*       obase = y + (size_t)b * Sdim * Cdim + lane * 2;
    if (ti == 0 || ti == NTb - 1) run_tile<true >(base, obase, t0);
    else                          run_tile<false>(base, obase, t0);
}

extern "C" void kernel_launch(void* const* d_in, const int* in_sizes, int n_in,
                              void* d_out, int out_size, void* d_ws, size_t ws_size,
                              hipStream_t stream) {
    const float* x = (const float*)d_in[0];
    float* y = (float*)d_out;
    // 1024 wave-tiles (32 batches x 32 tiles), 4 waves per 256-thread block
    mzs_kernel<<<dim3(256), dim3(256), 0, stream>>>(x, y);
}

// Round 16
// 53.097 us; speedup vs baseline: 1.1449x; 1.0087x over previous
//
#include <hip/hip_runtime.h>
#include <math.h>

// MovingZScoreNorm: x[32,8192,128] f32, W=24.
// mean: TF SAME avg-pool with valid-count; var: windowed sum of channel-summed
// sq / (W-1); out = (x-mean)/(sqrt(var)+eps).
//
// One wave per (batch, 256-row tile); lane owns 2 channels (float2).
// Per-lane variance running-sum; batched all-VALU 64-lane allreduce
// (permlane32/16 swap builtins + DPP row_ror tree) per 4 output rows.
//
// R16: prefetch depth 12 -> 24 steps. 4 rotating x-banks (48-row register
// delay line); load x(s+36) is first consumed (as x(s+12)) 24 steps later
// (~9000 cyc slack at 1 wave/SIMD) -- double the retirement slack for the
// in-order vmcnt queue (loads AND interleaved stores). launch_bounds(256,1)
// (1024 waves = 1/SIMD regardless; VGPR may exceed 128).
// Chunk schedule: period LCM(4 x-banks, 3 T-banks) = 12, rolled x2.

constexpr int Sdim = 8192;
constexpr int Cdim = 128;
constexpr int TT   = 256;            // output rows per wave
constexpr int NTb  = Sdim / TT;      // 32 tiles per batch
constexpr float EPSv = 1e-7f;

typedef unsigned int uintx2 __attribute__((ext_vector_type(2)));

template<bool EDGE>
__device__ __forceinline__ float2 ldg(const float* __restrict__ base, int r) {
    if (EDGE && (unsigned)r >= (unsigned)Sdim) return make_float2(0.f, 0.f);
    return *reinterpret_cast<const float2*>(base + (size_t)r * Cdim);
}

__device__ __forceinline__ void st2(float* p, float a, float b) {
    *reinterpret_cast<float2*>(p) = make_float2(a, b);
}

template<int N>
__device__ __forceinline__ float dpp_ror_add(float v) {
    int r = __builtin_amdgcn_update_dpp(0, __float_as_int(v),
                                        0x120 | N, 0xf, 0xf, true);
    return v + __int_as_float(r);
}

__device__ __forceinline__ float swap32_add(float v) {
    const unsigned u = __float_as_uint(v);
    uintx2 r = __builtin_amdgcn_permlane32_swap(u, u, false, false);
    return __uint_as_float(r.x) + __uint_as_float(r.y);  // v[l]+v[l^32]
}

__device__ __forceinline__ float swap16_add(float v) {
    const unsigned u = __float_as_uint(v);
    uintx2 r = __builtin_amdgcn_permlane16_swap(u, u, false, false);
    return __uint_as_float(r.x) + __uint_as_float(r.y);  // v[l]+v[l^16]
}

__device__ __forceinline__ float wave_allsum(float v) {
    v = swap32_add(v);
    v = swap16_add(v);
    v = dpp_ror_add<8>(v);
    v = dpp_ror_add<4>(v);
    v = dpp_ror_add<2>(v);
    v = dpp_ror_add<1>(v);
    return v;                // total of 64 lanes, in every lane
}

// One chunk of 12 iterations s = cb..cb+11.
// Xw[j]: x(s-12) (read, then overwritten with fresh x(s+36));
// Xm[j]: x(s); Xn[j]: x(s+12). (4th bank is pure in-flight, untouched here.)
// Tw[j] <- st_lane(s); Tr[j] gives st_lane(s-24).
// Lb[j]: read winsum(s-12), write winsum(s)  (12-delay).
template<bool EDGE>
__device__ __forceinline__ void chunk12(
    const float* __restrict__ base, float* __restrict__ obase,
    float2 (&Xw)[12], float2 (&Xm)[12], float2 (&Xn)[12],
    float (&Tw)[12], float (&Tr)[12], float2 (&Lb)[12],
    float2& lead, float& varsum, int cb, int t0, bool doLoad)
{
    float2 onum[4];
    float  vs4[4];
#pragma unroll
    for (int j = 0; j < 12; ++j) {
        const int s = cb + j;
        const float2 xold = Xw[j];                   // x(s-12)
        if (doLoad) Xw[j] = ldg<EDGE>(base, s + 36); // consumed 24 iters later
        const float2 xmid = Xn[j];                   // x(s+12)
        lead.x += xmid.x - xold.x;                   // lead -> winsum(s)
        lead.y += xmid.y - xold.y;
        const float2 xcur = Xm[j];                   // x(s)
        float invc;
        if (EDGE) {
            const int cnt = min(s + 12, Sdim - 1) - max(s - 11, 0) + 1;
            invc = __builtin_amdgcn_rcpf((float)cnt);
        } else {
            invc = 1.f / 24.f;
        }
        const float dx = xcur.x - lead.x * invc;
        const float dy = xcur.y - lead.y * invc;
        float st = dx * dx + dy * dy;                // PER-LANE (2 channels)
        if (EDGE && (unsigned)s >= (unsigned)Sdim) st = 0.f;
        varsum += st - Tr[j];                        // per-lane window sum
        Tw[j] = st;
        const float2 wq = Lb[j];                     // winsum(q), q = s-12
        Lb[j] = lead;
        float invq;
        if (EDGE) {
            const int q = s - 12;
            const int cq = min(q + 12, Sdim - 1) - max(q - 11, 0) + 1;
            invq = __builtin_amdgcn_rcpf((float)cq);
        } else {
            invq = 1.f / 24.f;
        }
        onum[j & 3].x = xold.x - wq.x * invq;        // (x(q) - mean(q))
        onum[j & 3].y = xold.y - wq.y * invq;
        vs4[j & 3] = varsum;

        if ((j & 3) == 3) {                          // batch of 4 output rows
            const int q0 = s - 15;
            if (q0 >= t0 && q0 < t0 + TT) {
                const float r0 = wave_allsum(vs4[0]);
                const float r1 = wave_allsum(vs4[1]);
                const float r2 = wave_allsum(vs4[2]);
                const float r3 = wave_allsum(vs4[3]);
                const float i0 = __builtin_amdgcn_rcpf(
                    __builtin_amdgcn_sqrtf(fmaxf(r0, 0.f) * (1.f / 23.f)) + EPSv);
                const float i1 = __builtin_amdgcn_rcpf(
                    __builtin_amdgcn_sqrtf(fmaxf(r1, 0.f) * (1.f / 23.f)) + EPSv);
                const float i2 = __builtin_amdgcn_rcpf(
                    __builtin_amdgcn_sqrtf(fmaxf(r2, 0.f) * (1.f / 23.f)) + EPSv);
                const float i3 = __builtin_amdgcn_rcpf(
                    __builtin_amdgcn_sqrtf(fmaxf(r3, 0.f) * (1.f / 23.f)) + EPSv);
                st2(obase + (size_t)(q0    ) * Cdim, onum[0].x * i0, onum[0].y * i0);
                st2(obase + (size_t)(q0 + 1) * Cdim, onum[1].x * i1, onum[1].y * i1);
                st2(obase + (size_t)(q0 + 2) * Cdim, onum[2].x * i2, onum[2].y * i2);
                st2(obase + (size_t)(q0 + 3) * Cdim, onum[3].x * i3, onum[3].y * i3);
            }
        }
    }
}

template<bool EDGE>
__device__ __forceinline__ void run_tile(
    const float* __restrict__ base, float* __restrict__ obase, int t0)
{
    float2 X0[12], X1[12], X2[12], X3[12], Lb[12];
    float  T0[12], T1[12], T2[12];
    float2 lead = make_float2(0.f, 0.f);
    float  varsum = 0.f;

    // Preload 48 rows: X0 = x(t0-24+j), X1 = x(t0-12+j), X2 = x(t0+j),
    // X3 = x(t0+12+j) (in-flight bank). lead = winsum(t0-13) = sum(X0+X1).
#pragma unroll
    for (int j = 0; j < 12; ++j) {
        X0[j] = ldg<EDGE>(base, t0 - 24 + j);
        X1[j] = ldg<EDGE>(base, t0 - 12 + j);
        X2[j] = ldg<EDGE>(base, t0 + j);
        X3[j] = ldg<EDGE>(base, t0 + 12 + j);
        T0[j] = 0.f; T1[j] = 0.f; T2[j] = 0.f;
        Lb[j] = make_float2(0.f, 0.f);
        lead.x += X0[j].x + X1[j].x;
        lead.y += X0[j].y + X1[j].y;
    }

    // 24 chunks of 12: s = t0-12 .. t0+275. Outputs q = t0 .. t0+255 (steps
    // past t0+267 are guard-skipped). Loads on chunks 0..21 (rows up to
    // t0+287 for interior; EDGE guards OOB). Bank roles at chunk c:
    // Xw=X[c%4], Xm=X[(c+1)%4], Xn=X[(c+2)%4]; Tw=T[c%3], Tr=T[(c+1)%3].
    int cb = t0 - 12;
#pragma unroll 1
    for (int r = 0; r < 2; ++r) {
        const bool lt = (r == 0);   // chunks 10,11 of each half: load only in r=0... 
        // (r=1 half: its k=10,11 are global chunks 22,23 -> no load)
        chunk12<EDGE>(base, obase, X0, X1, X2, T0, T1, Lb, lead, varsum, cb, t0, true); cb += 12; // k0
        chunk12<EDGE>(base, obase, X1, X2, X3, T1, T2, Lb, lead, varsum, cb, t0, true); cb += 12; // k1
        chunk12<EDGE>(base, obase, X2, X3, X0, T2, T0, Lb, lead, varsum, cb, t0, true); cb += 12; // k2
        chunk12<EDGE>(base, obase, X3, X0, X1, T0, T1, Lb, lead, varsum, cb, t0, true); cb += 12; // k3
        chunk12<EDGE>(base, obase, X0, X1, X2, T1, T2, Lb, lead, varsum, cb, t0, true); cb += 12; // k4
        chunk12<EDGE>(base, obase, X1, X2, X3, T2, T0, Lb, lead, varsum, cb, t0, true); cb += 12; // k5
        chunk12<EDGE>(base, obase, X2, X3, X0, T0, T1, Lb, lead, varsum, cb, t0, true); cb += 12; // k6
        chunk12<EDGE>(base, obase, X3, X0, X1, T1, T2, Lb, lead, varsum, cb, t0, true); cb += 12; // k7
        chunk12<EDGE>(base, obase, X0, X1, X2, T2, T0, Lb, lead, varsum, cb, t0, true); cb += 12; // k8
        chunk12<EDGE>(base, obase, X1, X2, X3, T0, T1, Lb, lead, varsum, cb, t0, true); cb += 12; // k9
        chunk12<EDGE>(base, obase, X2, X3, X0, T1, T2, Lb, lead, varsum, cb, t0, lt);   cb += 12; // k10
        chunk12<EDGE>(base, obase, X3, X0, X1, T2, T0, Lb, lead, varsum, cb, t0, lt);   cb += 12; // k11
    }
}

__global__ __launch_bounds__(256, 1)
void mzs_kernel(const float* __restrict__ x, float* __restrict__ y) {
    const int tid  = threadIdx.x;
    const int lane = tid & 63;
    const int wid  = blockIdx.x * 4 + (tid >> 6);   // 1024 waves
    const int b    = wid >> 5;                      // 32 tiles per batch
    const int ti   = wid & 31;
    const int t0   = ti * TT;
    const float* base  = x + (size_t)b * Sdim * Cdim + lane * 2;
    float*       obase = y + (size_t)b * Sdim * Cdim + lane * 2;
    if (ti == 0 || ti == NTb - 1) run_tile<true >(base, obase, t0);
    else                          run_tile<false>(base, obase, t0);
}

extern "C" void kernel_launch(void* const* d_in, const int* in_sizes, int n_in,
                              void* d_out, int out_size, void* d_ws, size_t ws_size,
                              hipStream_t stream) {
    const float* x = (const float*)d_in[0];
    float* y = (float*)d_out;
    // 1024 wave-tiles (32 batches x 32 tiles), 4 waves per 256-thread block
    mzs_kernel<<<dim3(256), dim3(256), 0, stream>>>(x, y);
}